// Round 14
// baseline (133.682 us; speedup 1.0000x reference)
//
#include <hip/hip_runtime.h>
#include <hip/hip_bf16.h>

#define SEGS   16384
#define DCH    128
#define CHUNK  32
#define SEGPB  4          // consecutive segments per block
#define FPITCH 132        // f32 plane pitch (528B rows, 16B-aligned, 2-way max)
#define XHBLK  520        // frag-layout block stride in shorts (8 blocks of 512+8 pad)
#define LOG2E  1.4426950408889634f

using f32x4  = __attribute__((ext_vector_type(4))) float;
using bf16x8 = __attribute__((ext_vector_type(8))) short;
using u32x2  = __attribute__((ext_vector_type(2))) unsigned int;
using u32x4  = __attribute__((ext_vector_type(4))) unsigned int;

__device__ __forceinline__ float u2f(unsigned int u) { return __uint_as_float(u); }
__device__ __forceinline__ unsigned int f2u(float f) { return __float_as_uint(f); }

// ---------------------------------------------------------------------------
// Setup: (a) W' = W * log2e -> fragment-ready bf16 (RTNE) B layout
//        (b) per-segment row starts via binary search on sorted index
// ---------------------------------------------------------------------------
__global__ void setup_kernel(const float* __restrict__ W,
                             const int* __restrict__ index, int N,
                             unsigned short* __restrict__ WfH,
                             int* __restrict__ seg_start) {
  int i = blockIdx.x * blockDim.x + threadIdx.x;
  if (i < DCH * DCH) {
    int n = i >> 7, k = i & 127;           // W[n][k]
    float w = W[i] * LOG2E;                // fold log2e -> raw exp2 in softmax
    unsigned int u = f2u(w);
    unsigned int r = (u + 0x7FFFu + ((u >> 16) & 1)) >> 16;  // RTNE bf16
    int kt    = k >> 5;
    int ntile = n >> 4;
    int lane  = (n & 15) + 16 * ((k >> 3) & 3);
    int j     = k & 7;
    int dst = ((kt * 8 + ntile) * 64 + lane) * 8 + j;
    WfH[dst] = (unsigned short)r;
  } else if (i < DCH * DCH + SEGS + 1) {
    int s = i - DCH * DCH;                 // lower_bound(index, s)
    int lo = 0, hi = N;
    while (lo < hi) {
      int mid = (lo + hi) >> 1;
      if (index[mid] < s) lo = mid + 1; else hi = mid;
    }
    seg_start[s] = lo;
  }
}

// ---------------------------------------------------------------------------
// Main: block b owns segments [4b, 4b+4) = contiguous rows [R0, R1).
// STREAMING CHUNKS (may cross segment boundaries; block-uniform masked sweep
// resolves boundaries and flushes per-segment results) + DEPTH-2 register
// prefetch: linear addresses make lookahead free — pvA/pvB ping-pong, chunk
// c+2's loads issued during chunk c, covering ~2 chunk iterations (> HBM
// ~900 cyc). Prefetches cross both raw barriers un-drained (no vmcnt).
// R10 LDS subsystem: xh = x_hi bf16 in MFMA-fragment layout; xf = exact f32.
// ---------------------------------------------------------------------------
__global__ __launch_bounds__(256) void pool_kernel(
    const float* __restrict__ x, const float* __restrict__ bias,
    const int* __restrict__ seg_start,
    const u32x4* __restrict__ WfH,
    float* __restrict__ out) {
  __shared__ unsigned short xh[8 * XHBLK];      // 8.32 KB
  __shared__ float          xf[CHUNK * FPITCH]; // 16.9 KB

  const int t    = threadIdx.x;
  const int wv   = t >> 6;
  const int lane = t & 63;
  const int cl   = lane & 15;              // C col within 16-tile (channel)
  const int g    = lane >> 4;              // lane group (k-slice / row group)
  const int k31  = t & 31;                 // staging lane-in-phase
  const int lrow = t >> 5;                 // staging rows 0..7 (+8 per p)
  const int lcol = k31 << 2;               // staging col (4 floats)

  const int xh_base = 1040 * (k31 >> 3) + 8 * lrow + 128 * ((k31 >> 1) & 3) + 4 * (k31 & 1);
  const int xf_base = lrow * FPITCH + lcol;
  const int frag_base = lane * 8;                    // shorts
  const int ex_base   = g * 4 * FPITCH + wv * 32 + cl;

  // Register-resident W fragments (this wave's 32 channels).
  u32x4 bh[4][2];
#pragma unroll
  for (int kt = 0; kt < 4; ++kt)
#pragma unroll
    for (int nt = 0; nt < 2; ++nt) {
      int off = (kt * 8 + (wv * 2 + nt)) * 64 + lane;   // 16B units
      bh[kt][nt] = WfH[off];
    }

  const float bc0 = bias[wv * 32 + cl]      * LOG2E;
  const float bc1 = bias[wv * 32 + 16 + cl] * LOG2E;

  const int s0   = blockIdx.x * SEGPB;
  const int sEnd = s0 + SEGPB;
  const int R0   = seg_start[s0];
  const int R1   = seg_start[sEnd];

  if (R0 == R1) {                          // whole block empty -> zeros
    if (lane < 16) {
      for (int es = s0; es < sEnd; ++es) {
        out[(size_t)es * DCH + wv * 32 + cl]      = 0.f;
        out[(size_t)es * DCH + wv * 32 + 16 + cl] = 0.f;
      }
    }
    return;
  }

  int curSeg = s0;
  int segEnd = seg_start[curSeg + 1];
  int c0 = R0;

  f32x4 pvA[4], pvB[4];
  auto issue = [&](f32x4 (&pv)[4], int base) {
#pragma unroll
    for (int p = 0; p < 4; ++p) {
      int lr = base + lrow + p * 8;
      f32x4 v = {0.f, 0.f, 0.f, 0.f};
      if (lr < R1) v = *(const f32x4*)(x + (size_t)lr * DCH + lcol);
      pv[p] = v;
    }
  };

  issue(pvA, R0);                          // chunk 0 in flight
  if (R0 + CHUNK < R1) issue(pvB, R0 + CHUNK);  // chunk 1 in flight

  float den[2] = {0.f, 0.f};
  float num[2] = {0.f, 0.f};

  // One pipeline step: stage pvS (chunk @ c0), refill pvS with chunk c0+2,
  // compute + sweep. Returns false when all segments flushed.
  auto body = [&](f32x4 (&pvS)[4]) -> bool {
    // ---- PHASE W: convert pvS -> xh (frag layout) + xf (f32 plane) ----
#pragma unroll
    for (int p = 0; p < 4; ++p) {
      f32x4 v = pvS[p];
      unsigned int u0 = f2u(v[0]), u1 = f2u(v[1]), u2 = f2u(v[2]), u3 = f2u(v[3]);
      u32x2 H = { (u1 & 0xFFFF0000u) | (u0 >> 16),
                  (u3 & 0xFFFF0000u) | (u2 >> 16) };
      *(u32x2*)&xh[xh_base + (p >> 1) * XHBLK + (p & 1) * 64] = H;
      *(f32x4*)&xf[xf_base + p * 8 * FPITCH] = v;
    }

    // ---- issue chunk c0+2 into pvS (linear lookahead; crosses barriers) ----
    if (c0 + 2 * CHUNK < R1) issue(pvS, c0 + 2 * CHUNK);

    // ---- barrier A: LDS writes visible; prefetches NOT drained ----
    asm volatile("s_waitcnt lgkmcnt(0)" ::: "memory");
    __builtin_amdgcn_sched_barrier(0);
    __builtin_amdgcn_s_barrier();
    __builtin_amdgcn_sched_barrier(0);

    // ---- PHASE R: att' = x @ W'^T + b' (this wave's 32 channels) ----
    f32x4 Cf[2][2];
#pragma unroll
    for (int mt = 0; mt < 2; ++mt) {
      Cf[mt][0] = (f32x4){bc0, bc0, bc0, bc0};
      Cf[mt][1] = (f32x4){bc1, bc1, bc1, bc1};
    }
#pragma unroll
    for (int kt = 0; kt < 4; ++kt) {
      u32x4 ah[2];
#pragma unroll
      for (int mt = 0; mt < 2; ++mt)
        ah[mt] = *(const u32x4*)&xh[frag_base + (2 * kt + mt) * XHBLK];
#pragma unroll
      for (int mt = 0; mt < 2; ++mt)
#pragma unroll
        for (int nt = 0; nt < 2; ++nt) {
          bf16x8 A = __builtin_bit_cast(bf16x8, ah[mt]);
          bf16x8 B = __builtin_bit_cast(bf16x8, bh[kt][nt]);
          Cf[mt][nt] = __builtin_amdgcn_mfma_f32_16x16x32_bf16(A, B, Cf[mt][nt], 0, 0, 0);
        }
    }

    // ---- p = exp2(att'), xv from f32 plane (once per chunk) ----
    float pr[2][2][4], xv[2][2][4];
#pragma unroll
    for (int nt = 0; nt < 2; ++nt)
#pragma unroll
      for (int mt = 0; mt < 2; ++mt)
#pragma unroll
        for (int r = 0; r < 4; ++r) {
          pr[nt][mt][r] = __builtin_amdgcn_exp2f(Cf[mt][nt][r]);
          xv[nt][mt][r] = xf[ex_base + (mt * 16 + r) * FPITCH + nt * 16];
        }

    // ---- segment sweep (block-uniform control flow) ----
    const int lim = c0 + CHUNK;
    int lo = c0;
    while (curSeg < sEnd) {
      const int hi  = segEnd;
      const int hiC = (hi < lim) ? hi : lim;
#pragma unroll
      for (int nt = 0; nt < 2; ++nt)
#pragma unroll
        for (int mt = 0; mt < 2; ++mt)
#pragma unroll
          for (int r = 0; r < 4; ++r) {
            const int row = c0 + mt * 16 + g * 4 + r;
            const bool use = (row >= lo) & (row < hiC);
            const float pp = use ? pr[nt][mt][r] : 0.f;
            den[nt] += pp;
            num[nt] += pp * xv[nt][mt][r];
          }
      if (hi <= lim) {                     // segment ends in this chunk: flush
#pragma unroll
        for (int nt = 0; nt < 2; ++nt) {
          float l = den[nt], a = num[nt];
          l += __shfl_xor(l, 16); l += __shfl_xor(l, 32);
          a += __shfl_xor(a, 16); a += __shfl_xor(a, 32);
          if (lane < 16)
            out[(size_t)curSeg * DCH + wv * 32 + nt * 16 + cl] = a / (l + 1e-16f);
          den[nt] = 0.f; num[nt] = 0.f;
        }
        lo = hi;
        ++curSeg;
        if (curSeg < sEnd) segEnd = seg_start[curSeg + 1];
      } else {
        break;                             // segment continues into next chunk
      }
    }
    if (curSeg >= sEnd) return false;      // all segments flushed -> done
    c0 += CHUNK;

    // ---- barrier B: all reads of this chunk done -> buffer reusable ----
    asm volatile("s_waitcnt lgkmcnt(0)" ::: "memory");
    __builtin_amdgcn_sched_barrier(0);
    __builtin_amdgcn_s_barrier();
    __builtin_amdgcn_sched_barrier(0);
    return true;
  };

  for (;;) {
    if (!body(pvA)) break;                 // even chunks stage pvA
    if (!body(pvB)) break;                 // odd chunks stage pvB
  }
}

extern "C" void kernel_launch(void* const* d_in, const int* in_sizes, int n_in,
                              void* d_out, int out_size, void* d_ws, size_t ws_size,
                              hipStream_t stream) {
  const float* x    = (const float*)d_in[0];
  const float* W    = (const float*)d_in[1];
  const float* bias = (const float*)d_in[2];
  const int*   idx  = (const int*)d_in[3];
  const int N = in_sizes[0] / DCH;

  unsigned short* WfH = (unsigned short*)d_ws;            // 32 KB
  int* seg = (int*)(WfH + DCH * DCH);                     // (SEGS+1)*4 B

  int setup_threads = DCH * DCH + SEGS + 1;
  setup_kernel<<<(setup_threads + 255) / 256, 256, 0, stream>>>(W, idx, N, WfH, seg);
  pool_kernel<<<SEGS / SEGPB, 256, 0, stream>>>(x, bias, seg,
                                                (const u32x4*)WfH,
                                                (float*)d_out);
}

// Round 15
// 130.863 us; speedup vs baseline: 1.0215x; 1.0215x over previous
//
#include <hip/hip_runtime.h>
#include <hip/hip_bf16.h>

#define SEGS   16384
#define DCH    128
#define NROWS  1000000
#define CHUNK  32
#define SEGPB  4          // consecutive segments per block
#define XHBLK  520        // frag-layout block stride in shorts (8 blocks of 512+8 pad)
#define LOG2E  1.4426950408889634f

using f32x4  = __attribute__((ext_vector_type(4))) float;
using bf16x8 = __attribute__((ext_vector_type(8))) short;
using u32x2  = __attribute__((ext_vector_type(2))) unsigned int;
using u32x4  = __attribute__((ext_vector_type(4))) unsigned int;

__device__ __forceinline__ float u2f(unsigned int u) { return __uint_as_float(u); }
__device__ __forceinline__ unsigned int f2u(float f) { return __float_as_uint(f); }

// ---------------------------------------------------------------------------
// Setup: (a) W' = W * log2e -> fragment-ready bf16 (RTNE) B layout
//        (b) per-segment row starts via binary search on sorted index
// ---------------------------------------------------------------------------
__global__ void setup_kernel(const float* __restrict__ W,
                             const int* __restrict__ index, int N,
                             unsigned short* __restrict__ WfH,
                             int* __restrict__ seg_start) {
  int i = blockIdx.x * blockDim.x + threadIdx.x;
  if (i < DCH * DCH) {
    int n = i >> 7, k = i & 127;           // W[n][k]
    float w = W[i] * LOG2E;                // fold log2e -> raw exp2 in softmax
    unsigned int u = f2u(w);
    unsigned int r = (u + 0x7FFFu + ((u >> 16) & 1)) >> 16;  // RTNE bf16
    int kt    = k >> 5;
    int ntile = n >> 4;
    int lane  = (n & 15) + 16 * ((k >> 3) & 3);
    int j     = k & 7;
    int dst = ((kt * 8 + ntile) * 64 + lane) * 8 + j;
    WfH[dst] = (unsigned short)r;
  } else if (i < DCH * DCH + SEGS + 1) {
    int s = i - DCH * DCH;                 // lower_bound(index, s)
    int lo = 0, hi = N;
    while (lo < hi) {
      int mid = (lo + hi) >> 1;
      if (index[mid] < s) lo = mid + 1; else hi = mid;
    }
    seg_start[s] = lo;
  }
}

// ---------------------------------------------------------------------------
// Main: block b owns segments [4b, 4b+4) = contiguous rows [R0, R1).
// Streaming 32-row chunks (may cross segment boundaries; block-uniform masked
// sweep flushes per-segment results). ONE raw barrier per chunk: xh (the only
// LDS buffer) is double-buffered; classic alternation makes barrier B
// unnecessary. The e*x values are GATHERED from global x (L1-hot: the same
// CU's pv loads fetched the chunk one iteration earlier); gathers are issued
// BEFORE the pv refill so the compiler's wait for them is vmcnt(4) and never
// drains the in-flight prefetch. e*x stays exact f32.
// ---------------------------------------------------------------------------
__global__ __launch_bounds__(256) void pool_kernel(
    const float* __restrict__ x, const float* __restrict__ bias,
    const int* __restrict__ seg_start,
    const u32x4* __restrict__ WfH,
    float* __restrict__ out) {
  __shared__ unsigned short xh[2][8 * XHBLK];   // 2 x 8.32 KB

  const int t    = threadIdx.x;
  const int wv   = t >> 6;
  const int lane = t & 63;
  const int cl   = lane & 15;              // C col within 16-tile (channel)
  const int g    = lane >> 4;              // lane group (k-slice / row group)
  const int k31  = t & 31;                 // staging lane-in-phase
  const int lrow = t >> 5;                 // staging rows 0..7 (+8 per p)
  const int lcol = k31 << 2;               // staging col (4 floats)

  const int xh_base = 1040 * (k31 >> 3) + 8 * lrow + 128 * ((k31 >> 1) & 3) + 4 * (k31 & 1);
  const int frag_base = lane * 8;          // shorts
  const int ch0 = wv * 32 + cl;            // e*x channel (nt=0); +16 for nt=1

  // Register-resident W fragments (this wave's 32 channels).
  u32x4 bh[4][2];
#pragma unroll
  for (int kt = 0; kt < 4; ++kt)
#pragma unroll
    for (int nt = 0; nt < 2; ++nt) {
      int off = (kt * 8 + (wv * 2 + nt)) * 64 + lane;   // 16B units
      bh[kt][nt] = WfH[off];
    }

  const float bc0 = bias[ch0]      * LOG2E;
  const float bc1 = bias[ch0 + 16] * LOG2E;

  const int s0   = blockIdx.x * SEGPB;
  const int sEnd = s0 + SEGPB;
  const int R0   = seg_start[s0];
  const int R1   = seg_start[sEnd];

  if (R0 == R1) {                          // whole block empty -> zeros
    if (lane < 16) {
      for (int es = s0; es < sEnd; ++es) {
        out[(size_t)es * DCH + wv * 32 + cl]      = 0.f;
        out[(size_t)es * DCH + wv * 32 + 16 + cl] = 0.f;
      }
    }
    return;
  }

  int curSeg = s0;
  int segEnd = seg_start[curSeg + 1];
  int c0 = R0;

  f32x4 pv[4];
  auto issue = [&](int base) {
#pragma unroll
    for (int p = 0; p < 4; ++p) {
      int lr = base + lrow + p * 8;
      f32x4 v = {0.f, 0.f, 0.f, 0.f};
      if (lr < R1) v = *(const f32x4*)(x + (size_t)lr * DCH + lcol);
      pv[p] = v;
    }
  };

  issue(R0);                               // chunk 0 in flight

  float den[2] = {0.f, 0.f};
  float num[2] = {0.f, 0.f};

  // One pipeline step: stage pv -> XH, gather e*x values for this chunk,
  // refill pv with next chunk, one barrier, compute + sweep.
  auto body = [&](unsigned short* XH) -> bool {
    // ---- PHASE W: convert pv -> XH (frag layout, b64 writes @ imm) ----
#pragma unroll
    for (int p = 0; p < 4; ++p) {
      f32x4 v = pv[p];
      unsigned int u0 = f2u(v[0]), u1 = f2u(v[1]), u2 = f2u(v[2]), u3 = f2u(v[3]);
      u32x2 H = { (u1 & 0xFFFF0000u) | (u0 >> 16),
                  (u3 & 0xFFFF0000u) | (u2 >> 16) };
      *(u32x2*)&XH[xh_base + (p >> 1) * XHBLK + (p & 1) * 64] = H;
    }

    // ---- gathers for THIS chunk's e*x (issued BEFORE pv refill so the
    //      compiler's wait for them leaves the pv prefetch in flight) ----
    float gx[2][2][4];
#pragma unroll
    for (int mt = 0; mt < 2; ++mt)
#pragma unroll
      for (int r = 0; r < 4; ++r) {
        int row = c0 + mt * 16 + g * 4 + r;
        row = (row < NROWS) ? row : (NROWS - 1);   // clamp: no fault, masked later
        const float* rp = x + (size_t)row * DCH;
        gx[0][mt][r] = rp[ch0];
        gx[1][mt][r] = rp[ch0 + 16];
      }

    // ---- refill pv with next chunk (linear stream; crosses the barrier) ----
    if (c0 + CHUNK < R1) issue(c0 + CHUNK);

    // ---- single barrier: XH writes visible; VMEM NOT drained ----
    asm volatile("s_waitcnt lgkmcnt(0)" ::: "memory");
    __builtin_amdgcn_sched_barrier(0);
    __builtin_amdgcn_s_barrier();
    __builtin_amdgcn_sched_barrier(0);

    // ---- PHASE R: att' = x @ W'^T + b' (this wave's 32 channels) ----
    f32x4 Cf[2][2];
#pragma unroll
    for (int mt = 0; mt < 2; ++mt) {
      Cf[mt][0] = (f32x4){bc0, bc0, bc0, bc0};
      Cf[mt][1] = (f32x4){bc1, bc1, bc1, bc1};
    }
#pragma unroll
    for (int kt = 0; kt < 4; ++kt) {
      u32x4 ah[2];
#pragma unroll
      for (int mt = 0; mt < 2; ++mt)
        ah[mt] = *(const u32x4*)&XH[frag_base + (2 * kt + mt) * XHBLK];
#pragma unroll
      for (int mt = 0; mt < 2; ++mt)
#pragma unroll
        for (int nt = 0; nt < 2; ++nt) {
          bf16x8 A = __builtin_bit_cast(bf16x8, ah[mt]);
          bf16x8 B = __builtin_bit_cast(bf16x8, bh[kt][nt]);
          Cf[mt][nt] = __builtin_amdgcn_mfma_f32_16x16x32_bf16(A, B, Cf[mt][nt], 0, 0, 0);
        }
    }

    // ---- p = exp2(att') (once per chunk) ----
    // C layout: col = lane&15 (channel), row(in 16-tile) = g*4 + reg [m89/m91]
    float pr[2][2][4];
#pragma unroll
    for (int nt = 0; nt < 2; ++nt)
#pragma unroll
      for (int mt = 0; mt < 2; ++mt)
#pragma unroll
        for (int r = 0; r < 4; ++r)
          pr[nt][mt][r] = __builtin_amdgcn_exp2f(Cf[mt][nt][r]);

    // ---- segment sweep (block-uniform control flow), e*x from gx ----
    const int lim = c0 + CHUNK;
    int lo = c0;
    while (curSeg < sEnd) {
      const int hi  = segEnd;
      const int hiC = (hi < lim) ? hi : lim;
#pragma unroll
      for (int nt = 0; nt < 2; ++nt)
#pragma unroll
        for (int mt = 0; mt < 2; ++mt)
#pragma unroll
          for (int r = 0; r < 4; ++r) {
            const int row = c0 + mt * 16 + g * 4 + r;
            const bool use = (row >= lo) & (row < hiC);
            const float pp = use ? pr[nt][mt][r] : 0.f;
            den[nt] += pp;
            num[nt] += pp * gx[nt][mt][r];
          }
      if (hi <= lim) {                     // segment ends in this chunk: flush
#pragma unroll
        for (int nt = 0; nt < 2; ++nt) {
          float l = den[nt], a = num[nt];
          l += __shfl_xor(l, 16); l += __shfl_xor(l, 32);
          a += __shfl_xor(a, 16); a += __shfl_xor(a, 32);
          if (lane < 16)
            out[(size_t)curSeg * DCH + wv * 32 + nt * 16 + cl] = a / (l + 1e-16f);
          den[nt] = 0.f; num[nt] = 0.f;
        }
        lo = hi;
        ++curSeg;
        if (curSeg < sEnd) segEnd = seg_start[curSeg + 1];
      } else {
        break;                             // segment continues into next chunk
      }
    }
    if (curSeg >= sEnd) return false;      // all segments flushed -> done
    c0 += CHUNK;
    return true;
  };

  for (;;) {
    if (!body(&xh[0][0])) break;           // even chunks use buffer 0
    if (!body(&xh[1][0])) break;           // odd chunks use buffer 1
  }
}

extern "C" void kernel_launch(void* const* d_in, const int* in_sizes, int n_in,
                              void* d_out, int out_size, void* d_ws, size_t ws_size,
                              hipStream_t stream) {
  const float* x    = (const float*)d_in[0];
  const float* W    = (const float*)d_in[1];
  const float* bias = (const float*)d_in[2];
  const int*   idx  = (const int*)d_in[3];
  const int N = in_sizes[0] / DCH;

  unsigned short* WfH = (unsigned short*)d_ws;            // 32 KB
  int* seg = (int*)(WfH + DCH * DCH);                     // (SEGS+1)*4 B

  int setup_threads = DCH * DCH + SEGS + 1;
  setup_kernel<<<(setup_threads + 255) / 256, 256, 0, stream>>>(W, idx, N, WfH, seg);
  pool_kernel<<<SEGS / SEGPB, 256, 0, stream>>>(x, bias, seg,
                                                (const u32x4*)WfH,
                                                (float*)d_out);
}